// Round 1
// baseline (820.641 us; speedup 1.0000x reference)
//
#include <hip/hip_runtime.h>

// GAT (heads=1) + mean-pool + FC, specialized:
//   pooled[f] = (1/N) * sum_e (ex_e / denom[dst_e]) * h[src_e][f] + b_gat[f]
//   out = relu(pooled @ W_fc + b_fc)
// segment_max skipped: alpha is invariant to the max-shift and |e| is O(10).

#define FHID 64
#define FOUT 72
#define AGG_BLOCKS 2048

// ---- kernel 1: h = x @ W (K=5); a_s = h.att_src; a_d = h.att_dst ----
__global__ __launch_bounds__(256) void k_node(
    const float* __restrict__ x, const float* __restrict__ W,
    const float* __restrict__ att_src, const float* __restrict__ att_dst,
    float* __restrict__ h, float* __restrict__ a_s, float* __restrict__ a_d,
    int N) {
  const int lane = threadIdx.x & 63;
  const int n = blockIdx.x * 4 + (threadIdx.x >> 6);
  if (n >= N) return;
  const float x0 = x[n * 5 + 0], x1 = x[n * 5 + 1], x2 = x[n * 5 + 2],
              x3 = x[n * 5 + 3], x4 = x[n * 5 + 4];
  float hv = x0 * W[0 * 64 + lane];
  hv += x1 * W[1 * 64 + lane];
  hv += x2 * W[2 * 64 + lane];
  hv += x3 * W[3 * 64 + lane];
  hv += x4 * W[4 * 64 + lane];
  h[(size_t)n * 64 + lane] = hv;
  float t1 = hv * att_src[lane];
  float t2 = hv * att_dst[lane];
#pragma unroll
  for (int o = 32; o > 0; o >>= 1) {
    t1 += __shfl_xor(t1, o, 64);
    t2 += __shfl_xor(t2, o, 64);
  }
  if (lane == 0) {
    a_s[n] = t1;
    a_d[n] = t2;
  }
}

// ---- kernel 2: per edge (incl. self loops): ex = exp(leakyrelu(a_s[s]+a_d[d]))
//      denom[d] += ex ----
__global__ __launch_bounds__(256) void k_edge(
    const int* __restrict__ ei, const float* __restrict__ a_s,
    const float* __restrict__ a_d, float* __restrict__ ex,
    float* __restrict__ denom, int E, int EP) {
  const int i = blockIdx.x * 256 + threadIdx.x;
  if (i >= EP) return;
  int s, d;
  if (i < E) {
    s = ei[i];
    d = ei[E + i];
  } else {
    s = i - E;
    d = s;
  }
  float e = a_s[s] + a_d[d];
  e = e > 0.f ? e : 0.2f * e;
  const float v = __expf(e);
  ex[i] = v;
  atomicAdd(&denom[d], v);
}

// ---- kernel 3: acc[f] += (ex/denom[dst]) * h[src][f], wave-per-edge-chunk ----
__global__ __launch_bounds__(256) void k_agg(
    const int* __restrict__ ei, const float* __restrict__ ex,
    const float* __restrict__ denom, const float* __restrict__ h,
    float* __restrict__ partial, int E, int EP) {
  const int lane = threadIdx.x & 63;
  const int lw = threadIdx.x >> 6;             // wave within block (0..3)
  const int wid = blockIdx.x * 4 + lw;         // global wave id
  const int nw = gridDim.x * 4;
  const int per = (EP + nw - 1) / nw;
  const int lo = wid * per;
  const int hi = (lo + per < EP) ? lo + per : EP;

  float acc = 0.f;
  for (int j = lo; j < hi; ++j) {
    int s, d;
    if (j < E) {
      s = ei[j];
      d = ei[E + j];
    } else {
      s = j - E;
      d = s;
    }
    const float w = ex[j] / (denom[d] + 1e-16f);
    acc += w * h[s * 64 + lane];
  }

  __shared__ float sacc[4][64];
  sacc[lw][lane] = acc;
  __syncthreads();
  if (threadIdx.x < 64) {
    const float t =
        sacc[0][lane] + sacc[1][lane] + sacc[2][lane] + sacc[3][lane];
    partial[blockIdx.x * 64 + lane] = t;
  }
}

// ---- kernel 4: reduce partials, /N + b_gat, FC 64->72 + relu ----
__global__ __launch_bounds__(128) void k_final(
    const float* __restrict__ partial, int nparts,
    const float* __restrict__ b_gat, const float* __restrict__ W_fc,
    const float* __restrict__ b_fc, float* __restrict__ out, float invN) {
  __shared__ float pooled[64];
  const int t = threadIdx.x;
  if (t < 64) {
    float s = 0.f;
    for (int b = 0; b < nparts; ++b) s += partial[b * 64 + t];
    pooled[t] = s * invN + b_gat[t];
  }
  __syncthreads();
  if (t < 72) {
    float s = b_fc[t];
#pragma unroll
    for (int f = 0; f < 64; ++f) s += pooled[f] * W_fc[f * 72 + t];
    out[t] = s > 0.f ? s : 0.f;
  }
}

extern "C" void kernel_launch(void* const* d_in, const int* in_sizes, int n_in,
                              void* d_out, int out_size, void* d_ws,
                              size_t ws_size, hipStream_t stream) {
  const float* x = (const float*)d_in[0];
  const int* ei = (const int*)d_in[1];
  const float* W = (const float*)d_in[2];
  const float* att_src = (const float*)d_in[3];
  const float* att_dst = (const float*)d_in[4];
  const float* b_gat = (const float*)d_in[5];
  const float* W_fc = (const float*)d_in[6];
  const float* b_fc = (const float*)d_in[7];
  float* out = (float*)d_out;

  const int N = in_sizes[0] / 5;   // 100000
  const int E = in_sizes[1] / 2;   // 1600000
  const int EP = E + N;            // edges + self loops

  char* p = (char*)d_ws;
  auto alloc = [&](size_t nbytes) -> void* {
    void* r = (void*)p;
    p += (nbytes + 255) & ~(size_t)255;
    return r;
  };
  float* h = (float*)alloc((size_t)N * 64 * sizeof(float));
  float* a_s = (float*)alloc((size_t)N * sizeof(float));
  float* a_d = (float*)alloc((size_t)N * sizeof(float));
  float* denom = (float*)alloc((size_t)N * sizeof(float));
  float* ex = (float*)alloc((size_t)EP * sizeof(float));
  float* partial = (float*)alloc((size_t)AGG_BLOCKS * 64 * sizeof(float));

  hipMemsetAsync(denom, 0, (size_t)N * sizeof(float), stream);
  k_node<<<(N + 3) / 4, 256, 0, stream>>>(x, W, att_src, att_dst, h, a_s, a_d,
                                          N);
  k_edge<<<(EP + 255) / 256, 256, 0, stream>>>(ei, a_s, a_d, ex, denom, E, EP);
  k_agg<<<AGG_BLOCKS, 256, 0, stream>>>(ei, ex, denom, h, partial, E, EP);
  k_final<<<1, 128, 0, stream>>>(partial, AGG_BLOCKS, b_gat, W_fc, b_fc, out,
                                 1.0f / (float)N);
}

// Round 2
// 336.272 us; speedup vs baseline: 2.4404x; 2.4404x over previous
//
#include <hip/hip_runtime.h>

// GAT (heads=1) + mean-pool + FC, specialized:
//   pooled[f] = (1/N) * sum_e (ex_e / denom[dst_e]) * h[src_e][f] + b_gat[f]
//   out = relu(pooled @ W_fc + b_fc)
// segment_max skipped: alpha is invariant to the max-shift and |e| is O(10).

#define FHID 64
#define FOUT 72
#define AGG_BLOCKS 2048

// ---- kernel 1: h = x @ W (K=5); a_s = h.att_src; a_d = h.att_dst ----
__global__ __launch_bounds__(256) void k_node(
    const float* __restrict__ x, const float* __restrict__ W,
    const float* __restrict__ att_src, const float* __restrict__ att_dst,
    float* __restrict__ h, float* __restrict__ a_s, float* __restrict__ a_d,
    int N) {
  const int lane = threadIdx.x & 63;
  const int n = blockIdx.x * 4 + (threadIdx.x >> 6);
  if (n >= N) return;
  const float x0 = x[n * 5 + 0], x1 = x[n * 5 + 1], x2 = x[n * 5 + 2],
              x3 = x[n * 5 + 3], x4 = x[n * 5 + 4];
  float hv = x0 * W[0 * 64 + lane];
  hv += x1 * W[1 * 64 + lane];
  hv += x2 * W[2 * 64 + lane];
  hv += x3 * W[3 * 64 + lane];
  hv += x4 * W[4 * 64 + lane];
  h[(size_t)n * 64 + lane] = hv;
  float t1 = hv * att_src[lane];
  float t2 = hv * att_dst[lane];
#pragma unroll
  for (int o = 32; o > 0; o >>= 1) {
    t1 += __shfl_xor(t1, o, 64);
    t2 += __shfl_xor(t2, o, 64);
  }
  if (lane == 0) {
    a_s[n] = t1;
    a_d[n] = t2;
  }
}

// ---- kernel 2: per edge (incl. self loops): ex = exp(leakyrelu(a_s[s]+a_d[d]))
//      denom[d] += ex ----
__global__ __launch_bounds__(256) void k_edge(
    const int* __restrict__ ei, const float* __restrict__ a_s,
    const float* __restrict__ a_d, float* __restrict__ ex,
    float* __restrict__ denom, int E, int EP) {
  const int i = blockIdx.x * 256 + threadIdx.x;
  if (i >= EP) return;
  int s, d;
  if (i < E) {
    s = ei[i];
    d = ei[E + i];
  } else {
    s = i - E;
    d = s;
  }
  float e = a_s[s] + a_d[d];
  e = e > 0.f ? e : 0.2f * e;
  const float v = __expf(e);
  ex[i] = v;
  atomicAdd(&denom[d], v);
}

// ---- kernel 3: acc[f] += (ex/denom[dst]) * h[src][f], wave-per-edge-chunk ----
__global__ __launch_bounds__(256) void k_agg(
    const int* __restrict__ ei, const float* __restrict__ ex,
    const float* __restrict__ denom, const float* __restrict__ h,
    float* __restrict__ partial, int E, int EP) {
  const int lane = threadIdx.x & 63;
  const int lw = threadIdx.x >> 6;             // wave within block (0..3)
  const int wid = blockIdx.x * 4 + lw;         // global wave id
  const int nw = gridDim.x * 4;
  const int per = (EP + nw - 1) / nw;
  const int lo = wid * per;
  const int hi = (lo + per < EP) ? lo + per : EP;

  float acc = 0.f;
  for (int j = lo; j < hi; ++j) {
    int s, d;
    if (j < E) {
      s = ei[j];
      d = ei[E + j];
    } else {
      s = j - E;
      d = s;
    }
    const float w = ex[j] / (denom[d] + 1e-16f);
    acc += w * h[s * 64 + lane];
  }

  __shared__ float sacc[4][64];
  sacc[lw][lane] = acc;
  __syncthreads();
  if (threadIdx.x < 64) {
    const float t =
        sacc[0][lane] + sacc[1][lane] + sacc[2][lane] + sacc[3][lane];
    partial[blockIdx.x * 64 + lane] = t;
  }
}

// ---- kernel 4a: pooled[f] = sum_b partial[b*64+f]  (one block per feature) ----
__global__ __launch_bounds__(256) void k_reduce(
    const float* __restrict__ partial, int nparts, float* __restrict__ pooled) {
  const int f = blockIdx.x;  // 0..63
  const int t = threadIdx.x;
  float s = 0.f;
  for (int b = t; b < nparts; b += 256) s += partial[b * 64 + f];
#pragma unroll
  for (int o = 32; o > 0; o >>= 1) s += __shfl_xor(s, o, 64);
  __shared__ float ws[4];
  if ((t & 63) == 0) ws[t >> 6] = s;
  __syncthreads();
  if (t == 0) pooled[f] = ws[0] + ws[1] + ws[2] + ws[3];
}

// ---- kernel 4b: /N + b_gat, FC 64->72 + relu ----
__global__ __launch_bounds__(128) void k_fc(
    const float* __restrict__ pooled_g, const float* __restrict__ b_gat,
    const float* __restrict__ W_fc, const float* __restrict__ b_fc,
    float* __restrict__ out, float invN) {
  __shared__ float pooled[64];
  const int t = threadIdx.x;
  if (t < 64) pooled[t] = pooled_g[t] * invN + b_gat[t];
  __syncthreads();
  if (t < 72) {
    float s = b_fc[t];
#pragma unroll
    for (int f = 0; f < 64; ++f) s += pooled[f] * W_fc[f * 72 + t];
    out[t] = s > 0.f ? s : 0.f;
  }
}

extern "C" void kernel_launch(void* const* d_in, const int* in_sizes, int n_in,
                              void* d_out, int out_size, void* d_ws,
                              size_t ws_size, hipStream_t stream) {
  const float* x = (const float*)d_in[0];
  const int* ei = (const int*)d_in[1];
  const float* W = (const float*)d_in[2];
  const float* att_src = (const float*)d_in[3];
  const float* att_dst = (const float*)d_in[4];
  const float* b_gat = (const float*)d_in[5];
  const float* W_fc = (const float*)d_in[6];
  const float* b_fc = (const float*)d_in[7];
  float* out = (float*)d_out;

  const int N = in_sizes[0] / 5;   // 100000
  const int E = in_sizes[1] / 2;   // 1600000
  const int EP = E + N;            // edges + self loops

  char* p = (char*)d_ws;
  auto alloc = [&](size_t nbytes) -> void* {
    void* r = (void*)p;
    p += (nbytes + 255) & ~(size_t)255;
    return r;
  };
  float* h = (float*)alloc((size_t)N * 64 * sizeof(float));
  float* a_s = (float*)alloc((size_t)N * sizeof(float));
  float* a_d = (float*)alloc((size_t)N * sizeof(float));
  float* denom = (float*)alloc((size_t)N * sizeof(float));
  float* ex = (float*)alloc((size_t)EP * sizeof(float));
  float* partial = (float*)alloc((size_t)AGG_BLOCKS * 64 * sizeof(float));
  float* pooled = (float*)alloc((size_t)64 * sizeof(float));

  hipMemsetAsync(denom, 0, (size_t)N * sizeof(float), stream);
  k_node<<<(N + 3) / 4, 256, 0, stream>>>(x, W, att_src, att_dst, h, a_s, a_d,
                                          N);
  k_edge<<<(EP + 255) / 256, 256, 0, stream>>>(ei, a_s, a_d, ex, denom, E, EP);
  k_agg<<<AGG_BLOCKS, 256, 0, stream>>>(ei, ex, denom, h, partial, E, EP);
  k_reduce<<<64, 256, 0, stream>>>(partial, AGG_BLOCKS, pooled);
  k_fc<<<1, 128, 0, stream>>>(pooled, b_gat, W_fc, b_fc, out, 1.0f / (float)N);
}

// Round 3
// 301.252 us; speedup vs baseline: 2.7241x; 1.1162x over previous
//
#include <hip/hip_runtime.h>

// GAT (heads=1) + mean-pool + FC, specialized.
// Key algebra: pooled[f] = (1/N) * sum_n c[n]*h[n][f] + b_gat[f]
//   where c[n] = sum_{edges e with src=n} exp(lrelu(a_s[src]+a_d[dst])) / denom[dst]
// so the per-edge h-row gather is replaced by scalar scatter-adds into c[]
// (L2-resident) plus ONE coalesced streaming pass over h.
// segment_max skipped: alpha is invariant to the max-shift and |e| is O(10).

#define POOL_BLOCKS 512

// ---- kernel 1: h = x @ W (K=5); a_s = h.att_src; a_d = h.att_dst ----
__global__ __launch_bounds__(256) void k_node(
    const float* __restrict__ x, const float* __restrict__ W,
    const float* __restrict__ att_src, const float* __restrict__ att_dst,
    float* __restrict__ h, float* __restrict__ a_s, float* __restrict__ a_d,
    int N) {
  const int lane = threadIdx.x & 63;
  const int n = blockIdx.x * 4 + (threadIdx.x >> 6);
  if (n >= N) return;
  const float x0 = x[n * 5 + 0], x1 = x[n * 5 + 1], x2 = x[n * 5 + 2],
              x3 = x[n * 5 + 3], x4 = x[n * 5 + 4];
  float hv = x0 * W[0 * 64 + lane];
  hv += x1 * W[1 * 64 + lane];
  hv += x2 * W[2 * 64 + lane];
  hv += x3 * W[3 * 64 + lane];
  hv += x4 * W[4 * 64 + lane];
  h[(size_t)n * 64 + lane] = hv;
  float t1 = hv * att_src[lane];
  float t2 = hv * att_dst[lane];
#pragma unroll
  for (int o = 32; o > 0; o >>= 1) {
    t1 += __shfl_xor(t1, o, 64);
    t2 += __shfl_xor(t2, o, 64);
  }
  if (lane == 0) {
    a_s[n] = t1;
    a_d[n] = t2;
  }
}

// ---- kernel 2: denom[d] += exp(lrelu(a_s[s]+a_d[d])) over edges+self-loops --
__global__ __launch_bounds__(256) void k_edge(
    const int* __restrict__ ei, const float* __restrict__ a_s,
    const float* __restrict__ a_d, float* __restrict__ denom, int E, int EP) {
  const int i = blockIdx.x * 256 + threadIdx.x;
  if (i >= EP) return;
  int s, d;
  if (i < E) {
    s = ei[i];
    d = ei[E + i];
  } else {
    s = i - E;
    d = s;
  }
  float e = a_s[s] + a_d[d];
  e = e > 0.f ? e : 0.2f * e;
  atomicAdd(&denom[d], __expf(e));
}

// ---- kernel 3: c[s] += exp(lrelu(...)) / denom[d] ----
__global__ __launch_bounds__(256) void k_scatter(
    const int* __restrict__ ei, const float* __restrict__ a_s,
    const float* __restrict__ a_d, const float* __restrict__ denom,
    float* __restrict__ c, int E, int EP) {
  const int i = blockIdx.x * 256 + threadIdx.x;
  if (i >= EP) return;
  int s, d;
  if (i < E) {
    s = ei[i];
    d = ei[E + i];
  } else {
    s = i - E;
    d = s;
  }
  float e = a_s[s] + a_d[d];
  e = e > 0.f ? e : 0.2f * e;
  const float w = __expf(e) / (denom[d] + 1e-16f);
  atomicAdd(&c[s], w);
}

// ---- kernel 4: partial[blk][f] = sum over node-chunk of c[n]*h[n][f] ----
// Wave handles 64-node chunks; c loaded coalesced per-lane then shfl-broadcast
// so all 64 h-row loads per chunk are independent (deep vmcnt pipeline).
__global__ __launch_bounds__(256) void k_pool(
    const float* __restrict__ c, const float* __restrict__ h,
    float* __restrict__ partial, int N) {
  const int lane = threadIdx.x & 63;
  const int lw = threadIdx.x >> 6;
  const int wid = blockIdx.x * 4 + lw;
  const int nw = gridDim.x * 4;
  const int nchunk = (N + 63) / 64;
  float acc = 0.f;
  for (int ch = wid; ch < nchunk; ch += nw) {
    const int base = ch * 64;
    const int nl = base + lane;
    const float cv = (nl < N) ? c[nl] : 0.f;
#pragma unroll 16
    for (int k = 0; k < 64; ++k) {
      const float wk = __shfl(cv, k, 64);
      int nn = base + k;
      nn = nn < N ? nn : N - 1;  // clamp (weight is 0 for OOB lanes)
      acc += wk * h[(size_t)nn * 64 + lane];
    }
  }
  __shared__ float sacc[4][64];
  sacc[lw][lane] = acc;
  __syncthreads();
  if (threadIdx.x < 64) {
    partial[blockIdx.x * 64 + lane] =
        sacc[0][lane] + sacc[1][lane] + sacc[2][lane] + sacc[3][lane];
  }
}

// ---- kernel 5: reduce partials, /N + b_gat, FC 64->72 + relu ----
__global__ __launch_bounds__(256) void k_finish(
    const float* __restrict__ partial, int nparts,
    const float* __restrict__ b_gat, const float* __restrict__ W_fc,
    const float* __restrict__ b_fc, float* __restrict__ out, float invN) {
  const int lane = threadIdx.x & 63;
  const int lw = threadIdx.x >> 6;
  float acc = 0.f;
  for (int b = lw; b < nparts; b += 4) acc += partial[b * 64 + lane];
  __shared__ float sacc[4][64];
  __shared__ float pooled[64];
  sacc[lw][lane] = acc;
  __syncthreads();
  if (threadIdx.x < 64) {
    pooled[threadIdx.x] =
        (sacc[0][threadIdx.x] + sacc[1][threadIdx.x] + sacc[2][threadIdx.x] +
         sacc[3][threadIdx.x]) *
            invN +
        b_gat[threadIdx.x];
  }
  __syncthreads();
  if (threadIdx.x < 72) {
    float s = b_fc[threadIdx.x];
#pragma unroll
    for (int f = 0; f < 64; ++f) s += pooled[f] * W_fc[f * 72 + threadIdx.x];
    out[threadIdx.x] = s > 0.f ? s : 0.f;
  }
}

extern "C" void kernel_launch(void* const* d_in, const int* in_sizes, int n_in,
                              void* d_out, int out_size, void* d_ws,
                              size_t ws_size, hipStream_t stream) {
  const float* x = (const float*)d_in[0];
  const int* ei = (const int*)d_in[1];
  const float* W = (const float*)d_in[2];
  const float* att_src = (const float*)d_in[3];
  const float* att_dst = (const float*)d_in[4];
  const float* b_gat = (const float*)d_in[5];
  const float* W_fc = (const float*)d_in[6];
  const float* b_fc = (const float*)d_in[7];
  float* out = (float*)d_out;

  const int N = in_sizes[0] / 5;  // 100000
  const int E = in_sizes[1] / 2;  // 1600000
  const int EP = E + N;           // edges + self loops

  char* p = (char*)d_ws;
  auto alloc = [&](size_t nbytes) -> void* {
    void* r = (void*)p;
    p += (nbytes + 255) & ~(size_t)255;
    return r;
  };
  float* h = (float*)alloc((size_t)N * 64 * sizeof(float));
  float* a_s = (float*)alloc((size_t)N * sizeof(float));
  float* a_d = (float*)alloc((size_t)N * sizeof(float));
  float* denom = (float*)alloc((size_t)N * sizeof(float));
  float* c = (float*)alloc((size_t)N * sizeof(float));
  float* partial = (float*)alloc((size_t)POOL_BLOCKS * 64 * sizeof(float));

  // denom and c are adjacent in the arena: one memset covers both.
  hipMemsetAsync(denom, 0, (size_t)((char*)c - (char*)denom) + (size_t)N * 4,
                 stream);
  k_node<<<(N + 3) / 4, 256, 0, stream>>>(x, W, att_src, att_dst, h, a_s, a_d,
                                          N);
  k_edge<<<(EP + 255) / 256, 256, 0, stream>>>(ei, a_s, a_d, denom, E, EP);
  k_scatter<<<(EP + 255) / 256, 256, 0, stream>>>(ei, a_s, a_d, denom, c, E,
                                                  EP);
  k_pool<<<POOL_BLOCKS, 256, 0, stream>>>(c, h, partial, N);
  k_finish<<<1, 256, 0, stream>>>(partial, POOL_BLOCKS, b_gat, W_fc, b_fc, out,
                                  1.0f / (float)N);
}

// Round 4
// 276.863 us; speedup vs baseline: 2.9641x; 1.0881x over previous
//
#include <hip/hip_runtime.h>

// GAT (heads=1) + mean-pool + FC, specialized.
//   pooled[f] = (1/N) * sum_n c[n]*h[n][f] + b_gat[f]
//   c[n] = sum_{edges e: src=n} exp(lrelu(a_s[src]+a_d[dst])) / denom[dst]
//   denom[d] = sum_{edges e: dst=d} ex_e   (+ self-loop terms)
// Device-scope scattered atomics are capped at 1/cycle/XCD (~19 G/s measured),
// so both scatter passes are done as multi-range LDS histograms (ds_add_f32)
// with non-atomic slab flush + coalesced reduce. Self loops are folded
// analytically into the reduce kernels (never streamed).
// segment_max skipped: alpha is invariant to the max-shift and |e| is O(10).

#define NRANGE 7
#define RSZ 14336  // 7*14336 = 100352 >= 100000; 57,344 B LDS
#define NBG 36     // blocks per range-group
#define NHBLK (NRANGE * NBG)  // 252
#define POOL_BLOCKS 512

// ---- kernel 1: h = x @ W (K=5); a_s = h.att_src; a_d = h.att_dst ----
__global__ __launch_bounds__(256) void k_node(
    const float* __restrict__ x, const float* __restrict__ W,
    const float* __restrict__ att_src, const float* __restrict__ att_dst,
    float* __restrict__ h, float* __restrict__ a_s, float* __restrict__ a_d,
    int N) {
  const int lane = threadIdx.x & 63;
  const int n = blockIdx.x * 4 + (threadIdx.x >> 6);
  if (n >= N) return;
  const float x0 = x[n * 5 + 0], x1 = x[n * 5 + 1], x2 = x[n * 5 + 2],
              x3 = x[n * 5 + 3], x4 = x[n * 5 + 4];
  float hv = x0 * W[0 * 64 + lane];
  hv += x1 * W[1 * 64 + lane];
  hv += x2 * W[2 * 64 + lane];
  hv += x3 * W[3 * 64 + lane];
  hv += x4 * W[4 * 64 + lane];
  h[(size_t)n * 64 + lane] = hv;
  float t1 = hv * att_src[lane];
  float t2 = hv * att_dst[lane];
#pragma unroll
  for (int o = 32; o > 0; o >>= 1) {
    t1 += __shfl_xor(t1, o, 64);
    t2 += __shfl_xor(t2, o, 64);
  }
  if (lane == 0) {
    a_s[n] = t1;
    a_d[n] = t2;
  }
}

// ---- histogram pass over edges; PASS=1: key=dst val=ex ; PASS=2: key=src
//      val=ex/denom[dst].  LDS-atomic accumulate, non-atomic slab flush. ----
template <int PASS>
__global__ __launch_bounds__(512) void k_hist(
    const int* __restrict__ ei, const float* __restrict__ a_s,
    const float* __restrict__ a_d, const float* __restrict__ denom,
    float* __restrict__ slab, int E) {
  __shared__ float hist[RSZ];
  const int g = blockIdx.x % NRANGE;
  const int bg = blockIdx.x / NRANGE;
  const int base = g * RSZ;
  for (int i = threadIdx.x; i < RSZ; i += 512) hist[i] = 0.f;
  __syncthreads();
  const int chunk = (E + NBG - 1) / NBG;
  const int lo = bg * chunk;
  const int hi = (lo + chunk < E) ? lo + chunk : E;
  for (int j = lo + threadIdx.x; j < hi; j += 512) {
    const int s = ei[j];
    const int d = ei[E + j];
    const int key = (PASS == 1) ? d : s;
    const unsigned ki = (unsigned)(key - base);
    if (ki < (unsigned)RSZ) {
      float e = a_s[s] + a_d[d];
      e = e > 0.f ? e : 0.2f * e;
      float v = __expf(e);
      if (PASS == 2) v /= (denom[d] + 1e-16f);
      atomicAdd(&hist[ki], v);
    }
  }
  __syncthreads();
  float* out = slab + (size_t)blockIdx.x * RSZ;
  for (int i = threadIdx.x; i < RSZ; i += 512) out[i] = hist[i];
}

// ---- reduce slabs; PASS=1 -> denom[n] (+ex_self); PASS=2 -> c[n]
//      (+ex_self/denom[n]) ----
template <int PASS>
__global__ __launch_bounds__(256) void k_red(
    const float* __restrict__ slab, const float* __restrict__ a_s,
    const float* __restrict__ a_d, const float* __restrict__ denom_in,
    float* __restrict__ outarr, int N) {
  const int n = blockIdx.x * 256 + threadIdx.x;
  if (n >= N) return;
  const int g = n / RSZ;
  const int i = n - g * RSZ;
  float sum = 0.f;
#pragma unroll 4
  for (int bg = 0; bg < NBG; ++bg)
    sum += slab[(size_t)(bg * NRANGE + g) * RSZ + i];
  float e = a_s[n] + a_d[n];
  e = e > 0.f ? e : 0.2f * e;
  const float ex_self = __expf(e);
  if (PASS == 1)
    outarr[n] = sum + ex_self;
  else
    outarr[n] = sum + ex_self / (denom_in[n] + 1e-16f);
}

// ---- pooled partial sums: partial[blk][f] = sum_chunk c[n]*h[n][f] ----
__global__ __launch_bounds__(256) void k_pool(
    const float* __restrict__ c, const float* __restrict__ h,
    float* __restrict__ partial, int N) {
  const int lane = threadIdx.x & 63;
  const int lw = threadIdx.x >> 6;
  const int wid = blockIdx.x * 4 + lw;
  const int nw = gridDim.x * 4;
  const int nchunk = (N + 63) / 64;
  float acc = 0.f;
  for (int ch = wid; ch < nchunk; ch += nw) {
    const int base = ch * 64;
    const int nl = base + lane;
    const float cv = (nl < N) ? c[nl] : 0.f;
#pragma unroll 16
    for (int k = 0; k < 64; ++k) {
      const float wk = __shfl(cv, k, 64);
      int nn = base + k;
      nn = nn < N ? nn : N - 1;  // clamp (weight is 0 for OOB lanes)
      acc += wk * h[(size_t)nn * 64 + lane];
    }
  }
  __shared__ float sacc[4][64];
  sacc[lw][lane] = acc;
  __syncthreads();
  if (threadIdx.x < 64) {
    partial[blockIdx.x * 64 + lane] =
        sacc[0][lane] + sacc[1][lane] + sacc[2][lane] + sacc[3][lane];
  }
}

// ---- reduce partials, /N + b_gat, FC 64->72 + relu ----
__global__ __launch_bounds__(256) void k_finish(
    const float* __restrict__ partial, int nparts,
    const float* __restrict__ b_gat, const float* __restrict__ W_fc,
    const float* __restrict__ b_fc, float* __restrict__ out, float invN) {
  const int lane = threadIdx.x & 63;
  const int lw = threadIdx.x >> 6;
  float acc = 0.f;
  for (int b = lw; b < nparts; b += 4) acc += partial[b * 64 + lane];
  __shared__ float sacc[4][64];
  __shared__ float pooled[64];
  sacc[lw][lane] = acc;
  __syncthreads();
  if (threadIdx.x < 64) {
    pooled[threadIdx.x] =
        (sacc[0][threadIdx.x] + sacc[1][threadIdx.x] + sacc[2][threadIdx.x] +
         sacc[3][threadIdx.x]) *
            invN +
        b_gat[threadIdx.x];
  }
  __syncthreads();
  if (threadIdx.x < 72) {
    float s = b_fc[threadIdx.x];
#pragma unroll
    for (int f = 0; f < 64; ++f) s += pooled[f] * W_fc[f * 72 + threadIdx.x];
    out[threadIdx.x] = s > 0.f ? s : 0.f;
  }
}

extern "C" void kernel_launch(void* const* d_in, const int* in_sizes, int n_in,
                              void* d_out, int out_size, void* d_ws,
                              size_t ws_size, hipStream_t stream) {
  const float* x = (const float*)d_in[0];
  const int* ei = (const int*)d_in[1];
  const float* W = (const float*)d_in[2];
  const float* att_src = (const float*)d_in[3];
  const float* att_dst = (const float*)d_in[4];
  const float* b_gat = (const float*)d_in[5];
  const float* W_fc = (const float*)d_in[6];
  const float* b_fc = (const float*)d_in[7];
  float* out = (float*)d_out;

  const int N = in_sizes[0] / 5;  // 100000
  const int E = in_sizes[1] / 2;  // 1600000

  char* p = (char*)d_ws;
  auto alloc = [&](size_t nbytes) -> void* {
    void* r = (void*)p;
    p += (nbytes + 255) & ~(size_t)255;
    return r;
  };
  float* h = (float*)alloc((size_t)N * 64 * sizeof(float));
  float* a_s = (float*)alloc((size_t)N * sizeof(float));
  float* a_d = (float*)alloc((size_t)N * sizeof(float));
  float* denom = (float*)alloc((size_t)N * sizeof(float));
  float* c = (float*)alloc((size_t)N * sizeof(float));
  float* slab = (float*)alloc((size_t)NHBLK * RSZ * sizeof(float));  // reused
  float* partial = (float*)alloc((size_t)POOL_BLOCKS * 64 * sizeof(float));

  k_node<<<(N + 3) / 4, 256, 0, stream>>>(x, W, att_src, att_dst, h, a_s, a_d,
                                          N);
  k_hist<1><<<NHBLK, 512, 0, stream>>>(ei, a_s, a_d, nullptr, slab, E);
  k_red<1><<<(N + 255) / 256, 256, 0, stream>>>(slab, a_s, a_d, nullptr, denom,
                                                N);
  k_hist<2><<<NHBLK, 512, 0, stream>>>(ei, a_s, a_d, denom, slab, E);
  k_red<2><<<(N + 255) / 256, 256, 0, stream>>>(slab, a_s, a_d, denom, c, N);
  k_pool<<<POOL_BLOCKS, 256, 0, stream>>>(c, h, partial, N);
  k_finish<<<1, 256, 0, stream>>>(partial, POOL_BLOCKS, b_gat, W_fc, b_fc, out,
                                  1.0f / (float)N);
}

// Round 5
// 218.020 us; speedup vs baseline: 3.7641x; 1.2699x over previous
//
#include <hip/hip_runtime.h>

// GAT (heads=1) + mean-pool + FC, specialized.
//   pooled[f] = (1/N) * sum_n c[n]*h[n][f] + b_gat[f]
//   c[n] = sum_{edges e: src=n} ex_e * rden[dst_e]
//   rden[d] = 1 / (sum_{edges e: dst=d} ex_e + ex_self_d + 1e-16)
// Device-scope scattered atomics cap at ~19 G/s (1/cyc/XCD), so both scatter
// passes are multi-range LDS histograms (ds_add_f32) + non-atomic slab flush +
// coalesced reduce. Self loops folded analytically into the reduce kernels.
// Range-blocks of one chunk share blockIdx%8 so they land on one XCD (L2 reuse).
// segment_max skipped: alpha invariant to max-shift; |e| is O(10) -> exp safe.

#define NRANGE 8
#define RSZ 12544           // 8*12544 = 100352 >= N ; 50,176 B LDS -> 3 blk/CU
#define HTHREADS 512
#define GMAX 96             // chunk groups (multiple of 8)
#define POOL_BLOCKS 512

// ---- kernel 1: h = x @ W (K=5); a_s = h.att_src; a_d = h.att_dst ----
__global__ __launch_bounds__(256) void k_node(
    const float* __restrict__ x, const float* __restrict__ W,
    const float* __restrict__ att_src, const float* __restrict__ att_dst,
    float* __restrict__ h, float* __restrict__ a_s, float* __restrict__ a_d,
    int N) {
  const int lane = threadIdx.x & 63;
  const int n = blockIdx.x * 4 + (threadIdx.x >> 6);
  if (n >= N) return;
  const float x0 = x[n * 5 + 0], x1 = x[n * 5 + 1], x2 = x[n * 5 + 2],
              x3 = x[n * 5 + 3], x4 = x[n * 5 + 4];
  float hv = x0 * W[0 * 64 + lane];
  hv += x1 * W[1 * 64 + lane];
  hv += x2 * W[2 * 64 + lane];
  hv += x3 * W[3 * 64 + lane];
  hv += x4 * W[4 * 64 + lane];
  h[(size_t)n * 64 + lane] = hv;
  float t1 = hv * att_src[lane];
  float t2 = hv * att_dst[lane];
#pragma unroll
  for (int o = 32; o > 0; o >>= 1) {
    t1 += __shfl_xor(t1, o, 64);
    t2 += __shfl_xor(t2, o, 64);
  }
  if (lane == 0) {
    a_s[n] = t1;
    a_d[n] = t2;
  }
}

// ---- histogram pass; PASS=1: key=dst val=ex ; PASS=2: key=src val=ex*rden[d]
// grid = NRANGE*G. Decode so the 8 range-blocks of a chunk share blockIdx%8
// (=> same XCD under round-robin dispatch => chunk re-reads hit local L2).
template <int PASS>
__global__ __launch_bounds__(HTHREADS) void k_hist(
    const int* __restrict__ ei, const float* __restrict__ a_s,
    const float* __restrict__ a_d, const float* __restrict__ rden,
    float* __restrict__ slab, int E, int G) {
  __shared__ float hist[RSZ];
  const int b = blockIdx.x;
  const int x = b & 7;
  const int q = b >> 3;             // 0..G-1
  const int g = q & 7;              // range id 0..7
  const int bg = ((q >> 3) << 3) + x;  // chunk id 0..G-1
  const int base = g * RSZ;
  for (int i = threadIdx.x; i < RSZ; i += HTHREADS) hist[i] = 0.f;
  __syncthreads();
  const int chunk = (E + G - 1) / G;
  const int lo = bg * chunk;
  const int hi = (lo + chunk < E) ? lo + chunk : E;
#pragma unroll 4
  for (int j = lo + threadIdx.x; j < hi; j += HTHREADS) {
    const int s = ei[j];
    const int d = ei[E + j];
    const int key = (PASS == 1) ? d : s;
    const unsigned ki = (unsigned)(key - base);
    if (ki < (unsigned)RSZ) {
      float e = a_s[s] + a_d[d];
      e = e > 0.f ? e : 0.2f * e;
      float v = __expf(e);
      if (PASS == 2) v *= rden[d];
      atomicAdd(&hist[ki], v);
    }
  }
  __syncthreads();
  float* outp = slab + ((size_t)g * G + bg) * RSZ;
  for (int i = threadIdx.x; i < RSZ; i += HTHREADS) outp[i] = hist[i];
}

// ---- reduce slabs; PASS=1 -> rden[n] = 1/(sum+ex_self+eps);
//      PASS=2 -> c[n] = sum + ex_self*rden[n] ----
template <int PASS>
__global__ __launch_bounds__(256) void k_red(
    const float* __restrict__ slab, const float* __restrict__ a_s,
    const float* __restrict__ a_d, const float* __restrict__ rden_in,
    float* __restrict__ outarr, int N, int G) {
  const int n = blockIdx.x * 256 + threadIdx.x;
  if (n >= N) return;
  const int g = n / RSZ;
  const int i = n - g * RSZ;
  const float* sp = slab + ((size_t)g * G) * RSZ + i;
  float sum = 0.f;
#pragma unroll 8
  for (int bg = 0; bg < G; ++bg) sum += sp[(size_t)bg * RSZ];
  float e = a_s[n] + a_d[n];
  e = e > 0.f ? e : 0.2f * e;
  const float ex_self = __expf(e);
  if (PASS == 1)
    outarr[n] = 1.0f / (sum + ex_self + 1e-16f);
  else
    outarr[n] = sum + ex_self * rden_in[n];
}

// ---- pooled partial sums: partial[blk][f] = sum_chunk c[n]*h[n][f] ----
__global__ __launch_bounds__(256) void k_pool(
    const float* __restrict__ c, const float* __restrict__ h,
    float* __restrict__ partial, int N) {
  const int lane = threadIdx.x & 63;
  const int lw = threadIdx.x >> 6;
  const int wid = blockIdx.x * 4 + lw;
  const int nw = gridDim.x * 4;
  const int nchunk = (N + 63) / 64;
  float acc = 0.f;
  for (int ch = wid; ch < nchunk; ch += nw) {
    const int base = ch * 64;
    const int nl = base + lane;
    const float cv = (nl < N) ? c[nl] : 0.f;
#pragma unroll 16
    for (int k = 0; k < 64; ++k) {
      const float wk = __shfl(cv, k, 64);
      int nn = base + k;
      nn = nn < N ? nn : N - 1;  // clamp (weight is 0 for OOB lanes)
      acc += wk * h[(size_t)nn * 64 + lane];
    }
  }
  __shared__ float sacc[4][64];
  sacc[lw][lane] = acc;
  __syncthreads();
  if (threadIdx.x < 64) {
    partial[blockIdx.x * 64 + lane] =
        sacc[0][lane] + sacc[1][lane] + sacc[2][lane] + sacc[3][lane];
  }
}

// ---- reduce partials, /N + b_gat, FC 64->72 + relu ----
__global__ __launch_bounds__(256) void k_finish(
    const float* __restrict__ partial, int nparts,
    const float* __restrict__ b_gat, const float* __restrict__ W_fc,
    const float* __restrict__ b_fc, float* __restrict__ out, float invN) {
  const int lane = threadIdx.x & 63;
  const int lw = threadIdx.x >> 6;
  float acc = 0.f;
  for (int b = lw; b < nparts; b += 4) acc += partial[b * 64 + lane];
  __shared__ float sacc[4][64];
  __shared__ float pooled[64];
  sacc[lw][lane] = acc;
  __syncthreads();
  if (threadIdx.x < 64) {
    pooled[threadIdx.x] =
        (sacc[0][threadIdx.x] + sacc[1][threadIdx.x] + sacc[2][threadIdx.x] +
         sacc[3][threadIdx.x]) *
            invN +
        b_gat[threadIdx.x];
  }
  __syncthreads();
  if (threadIdx.x < 72) {
    float s = b_fc[threadIdx.x];
#pragma unroll
    for (int f = 0; f < 64; ++f) s += pooled[f] * W_fc[f * 72 + threadIdx.x];
    out[threadIdx.x] = s > 0.f ? s : 0.f;
  }
}

extern "C" void kernel_launch(void* const* d_in, const int* in_sizes, int n_in,
                              void* d_out, int out_size, void* d_ws,
                              size_t ws_size, hipStream_t stream) {
  const float* x = (const float*)d_in[0];
  const int* ei = (const int*)d_in[1];
  const float* W = (const float*)d_in[2];
  const float* att_src = (const float*)d_in[3];
  const float* att_dst = (const float*)d_in[4];
  const float* b_gat = (const float*)d_in[5];
  const float* W_fc = (const float*)d_in[6];
  const float* b_fc = (const float*)d_in[7];
  float* out = (float*)d_out;

  const int N = in_sizes[0] / 5;  // 100000
  const int E = in_sizes[1] / 2;  // 1600000

  char* p = (char*)d_ws;
  auto alloc = [&](size_t nbytes) -> void* {
    void* r = (void*)p;
    p += (nbytes + 255) & ~(size_t)255;
    return r;
  };
  float* h = (float*)alloc((size_t)N * 64 * sizeof(float));
  float* a_s = (float*)alloc((size_t)N * sizeof(float));
  float* a_d = (float*)alloc((size_t)N * sizeof(float));
  float* rden = (float*)alloc((size_t)N * sizeof(float));
  float* c = (float*)alloc((size_t)N * sizeof(float));
  float* partial = (float*)alloc((size_t)POOL_BLOCKS * 64 * sizeof(float));

  // slab gets the rest of ws; shrink G (multiple of 8) if ws is tight.
  const size_t used = (size_t)(p - (char*)d_ws);
  const size_t avail = (ws_size > used) ? ws_size - used : 0;
  const size_t per_g = (size_t)NRANGE * RSZ * sizeof(float);  // 401,408 B
  int G = (int)(avail / per_g);
  G = (G / 8) * 8;
  if (G > GMAX) G = GMAX;
  if (G < 8) G = 8;  // 3.2 MB minimum; prior rounds confirm ws >> this
  float* slab = (float*)alloc((size_t)G * per_g);

  k_node<<<(N + 3) / 4, 256, 0, stream>>>(x, W, att_src, att_dst, h, a_s, a_d,
                                          N);
  k_hist<1><<<NRANGE * G, HTHREADS, 0, stream>>>(ei, a_s, a_d, nullptr, slab,
                                                 E, G);
  k_red<1><<<(N + 255) / 256, 256, 0, stream>>>(slab, a_s, a_d, nullptr, rden,
                                                N, G);
  k_hist<2><<<NRANGE * G, HTHREADS, 0, stream>>>(ei, a_s, a_d, rden, slab, E,
                                                 G);
  k_red<2><<<(N + 255) / 256, 256, 0, stream>>>(slab, a_s, a_d, rden, c, N, G);
  k_pool<<<POOL_BLOCKS, 256, 0, stream>>>(c, h, partial, N);
  k_finish<<<1, 256, 0, stream>>>(partial, POOL_BLOCKS, b_gat, W_fc, b_fc, out,
                                  1.0f / (float)N);
}